// Round 1
// baseline (31.541 us; speedup 1.0000x reference)
//
#include <hip/hip_runtime.h>

// Polyphase resampler 16000 -> 14400 Hz (SpeedPerturb).
// gcd = 1600 -> conv_stride = 10, P = 9 output phases, filter width W = 14.
// out[b, m*9+p] = sum_{w<14} wav[b, fi[p] + 10*m + w] * weights[p][w]
// with zero padding outside [0, N). fi = {-6,-5,-4,-3,-2,-1,0,2,3}.

#define RS_P 9
#define RS_W 14
#define RS_STRIDE 10
#define RS_TPB 256
// max input span for 256 consecutive outputs:
// 10 * ceil(255/9 + 1) + (fi_max - fi_min) + W = 10*29 + 9 + 14 = 313
#define RS_SPAN 320

__global__ __launch_bounds__(RS_TPB) void resample_kernel(
    const float* __restrict__ wav, const float* __restrict__ wgt,
    float* __restrict__ out, int N, int TOT) {
  __shared__ float s_w[RS_P * RS_W];  // 126 floats
  __shared__ float s_in[RS_SPAN];

  const int fi[RS_P] = {-6, -5, -4, -3, -2, -1, 0, 2, 3};

  const int b = blockIdx.y;
  const int t0 = blockIdx.x * RS_TPB;

  if (threadIdx.x < RS_P * RS_W) s_w[threadIdx.x] = wgt[threadIdx.x];

  // Input range needed by outputs [t0, min(t0+255, TOT-1)]
  const int m0 = t0 / RS_P;
  int t1 = t0 + RS_TPB - 1;
  if (t1 > TOT - 1) t1 = TOT - 1;
  const int m1 = t1 / RS_P;
  const int in_start = RS_STRIDE * m0 - 6;                 // fi_min = -6
  const int span = RS_STRIDE * (m1 - m0) + 9 + RS_W;       // fi_max - fi_min = 9

  const float* wrow = wav + (size_t)b * N;
  for (int i = threadIdx.x; i < span; i += RS_TPB) {
    const int gi = in_start + i;
    s_in[i] = (gi >= 0 && gi < N) ? wrow[gi] : 0.0f;
  }
  __syncthreads();

  const int t = t0 + threadIdx.x;
  if (t < TOT) {
    const int m = t / RS_P;
    const int p = t - RS_P * m;
    const int base = fi[p] + RS_STRIDE * m - in_start;
    const float* wp = &s_w[p * RS_W];
    float acc = 0.0f;
#pragma unroll
    for (int w = 0; w < RS_W; ++w) acc = fmaf(s_in[base + w], wp[w], acc);
    out[(size_t)b * TOT + t] = acc;
  }
}

extern "C" void kernel_launch(void* const* d_in, const int* in_sizes, int n_in,
                              void* d_out, int out_size, void* d_ws, size_t ws_size,
                              hipStream_t stream) {
  const float* wav = (const float*)d_in[0];
  const float* wgt = (const float*)d_in[1];
  float* out = (float*)d_out;

  const int N = 480000;
  const int B = in_sizes[0] / N;       // 16
  const int TOT = out_size / B;        // 432000

  dim3 grid((TOT + RS_TPB - 1) / RS_TPB, B);
  resample_kernel<<<grid, RS_TPB, 0, stream>>>(wav, wgt, out, N, TOT);
}

// Round 2
// 24.829 us; speedup vs baseline: 1.2703x; 1.2703x over previous
//
#include <hip/hip_runtime.h>

// Polyphase resampler 16000 -> 14400 Hz (SpeedPerturb).
// conv_stride = 10, P = 9 phases, W = 14 taps.
// out[b, t] = sum_{w<14} wav[b, base(t) + w] * weights[t%9][w]
// where base(t) = (10*t + 2)/9 - 6   (== fi[t%9] + 10*(t/9), verified p=0..8)
// zero-padded outside [0, N).

#define RS_P 9
#define RS_W 14
#define RS_TPB 256
#define RS_OPT 4                    // outputs per thread
#define RS_OPB (RS_TPB * RS_OPT)    // 1024 outputs per block
// input span for 1024 outputs: 10*ceil(1023/9 + 1) + 9 + 14 = 1163; +3 align
#define RS_SPAN4 293                // float4 slots (1172 floats)

__global__ __launch_bounds__(RS_TPB) void resample_kernel(
    const float* __restrict__ wav, const float* __restrict__ wgt,
    float* __restrict__ out, int N, int TOT) {
  __shared__ float s_w[RS_P * RS_W];        // 126 floats
  __shared__ float s_in[RS_SPAN4 * 4];

  const int b = blockIdx.y;
  const int t0 = blockIdx.x * RS_OPB;
  const int tid = threadIdx.x;

  if (tid < RS_P * RS_W) s_w[tid] = wgt[tid];

  // Input range needed by outputs [t0, min(t0+RS_OPB-1, TOT-1)]
  const int m0 = (unsigned)t0 / 9u;
  int t1 = t0 + RS_OPB - 1;
  if (t1 > TOT - 1) t1 = TOT - 1;
  const int m1 = (unsigned)t1 / 9u;
  const int in_start = 10 * m0 - 6;          // fi_min = -6
  const int aligned = in_start & ~3;         // float4-aligned global base of s_in[0]
  const int end = in_start + 10 * (m1 - m0) + 23;  // one past max index needed
  const int n4 = (end - aligned + 3) >> 2;

  const float* wrow = wav + (size_t)b * N;
  for (int i4 = tid; i4 < n4; i4 += RS_TPB) {
    const int gi = aligned + (i4 << 2);
    float4 v;
    if (gi >= 0 && gi + 3 < N) {
      v = *reinterpret_cast<const float4*>(wrow + gi);
    } else {
      v.x = (gi + 0 >= 0 && gi + 0 < N) ? wrow[gi + 0] : 0.0f;
      v.y = (gi + 1 >= 0 && gi + 1 < N) ? wrow[gi + 1] : 0.0f;
      v.z = (gi + 2 >= 0 && gi + 2 < N) ? wrow[gi + 2] : 0.0f;
      v.w = (gi + 3 >= 0 && gi + 3 < N) ? wrow[gi + 3] : 0.0f;
    }
    *reinterpret_cast<float4*>(&s_in[i4 << 2]) = v;
  }
  __syncthreads();

  const int t = t0 + (tid << 2);
  if (t < TOT) {
    int m = (unsigned)t / 9u;
    int p = t - 9 * m;
    float4 o;
    float* po = &o.x;
#pragma unroll
    for (int j = 0; j < RS_OPT; ++j) {
      const int tj = t + j;
      const int base = (int)((10u * (unsigned)tj + 2u) / 9u) - 6 - aligned;
      const float* wp = &s_w[p * RS_W];
      float acc = 0.0f;
#pragma unroll
      for (int w = 0; w < RS_W; ++w) acc = fmaf(s_in[base + w], wp[w], acc);
      po[j] = acc;
      if (++p == RS_P) p = 0;
    }
    *reinterpret_cast<float4*>(&out[(size_t)b * TOT + t]) = o;
  }
}

extern "C" void kernel_launch(void* const* d_in, const int* in_sizes, int n_in,
                              void* d_out, int out_size, void* d_ws, size_t ws_size,
                              hipStream_t stream) {
  const float* wav = (const float*)d_in[0];
  const float* wgt = (const float*)d_in[1];
  float* out = (float*)d_out;

  const int N = 480000;
  const int B = in_sizes[0] / N;       // 16
  const int TOT = out_size / B;        // 432000

  dim3 grid((TOT + RS_OPB - 1) / RS_OPB, B);
  resample_kernel<<<grid, RS_TPB, 0, stream>>>(wav, wgt, out, N, TOT);
}

// Round 3
// 15.711 us; speedup vs baseline: 2.0076x; 1.5804x over previous
//
#include <hip/hip_runtime.h>

// Polyphase resampler 16000 -> 14400 Hz (SpeedPerturb).
// stride 10, P = 9 phases, W = 14 taps.
// Thread owns one period m: outputs t = 9m+j, j=0..8 (phase == j).
// out[t] = sum_w wav[10m - 6 + OFF[j] + w] * wgt[14 j + w],
// OFF = {0,1,2,3,4,5,6,8,9}; window = 24 floats, 8B-aligned (10m-6 even).

#define RS_TPB 256

__global__ __launch_bounds__(RS_TPB) void resample_kernel(
    const float* __restrict__ wav, const float* __restrict__ wgt,
    float* __restrict__ out, int N, int M, int TOT) {
  __shared__ float s_out[RS_TPB * 9];  // 9216 B

  const int b = blockIdx.y;
  const int m0 = blockIdx.x * RS_TPB;
  const int tid = threadIdx.x;
  const int m = m0 + tid;
  const float* __restrict__ wrow = wav + (size_t)b * N;

  if (m < M) {
    const int gbase = 10 * m - 6;
    float win[24];
    if (gbase >= 0 && gbase + 24 <= N) {
#pragma unroll
      for (int k = 0; k < 12; ++k) {
        const float2 v = *reinterpret_cast<const float2*>(wrow + gbase + 2 * k);
        win[2 * k] = v.x;
        win[2 * k + 1] = v.y;
      }
    } else {
#pragma unroll
      for (int k = 0; k < 24; ++k) {
        const int gi = gbase + k;
        win[k] = (gi >= 0 && gi < N) ? wrow[gi] : 0.0f;
      }
    }
    const int OFF[9] = {0, 1, 2, 3, 4, 5, 6, 8, 9};
#pragma unroll
    for (int j = 0; j < 9; ++j) {
      float acc = 0.0f;
#pragma unroll
      for (int w = 0; w < 14; ++w)
        acc = fmaf(win[OFF[j] + w], wgt[14 * j + w], acc);
      s_out[tid * 9 + j] = acc;
    }
  }
  __syncthreads();

  // Coalesced float4 store of this block's contiguous output slab.
  int n_out = M - m0;
  if (n_out > RS_TPB) n_out = RS_TPB;
  n_out *= 9;  // block m-count is a multiple of 4 except possibly last (128): ok
  const size_t obase = (size_t)b * TOT + (size_t)m0 * 9;
  const int n4 = n_out >> 2;
  float* __restrict__ orow = out + obase;
  for (int i4 = tid; i4 < n4; i4 += RS_TPB) {
    const float4 v = *reinterpret_cast<const float4*>(&s_out[i4 << 2]);
    *reinterpret_cast<float4*>(orow + (i4 << 2)) = v;
  }
  // scalar tail (only if n_out % 4 != 0; absent for these sizes)
  for (int i = (n4 << 2) + tid; i < n_out; i += RS_TPB) orow[i] = s_out[i];
}

extern "C" void kernel_launch(void* const* d_in, const int* in_sizes, int n_in,
                              void* d_out, int out_size, void* d_ws, size_t ws_size,
                              hipStream_t stream) {
  const float* wav = (const float*)d_in[0];
  const float* wgt = (const float*)d_in[1];
  float* out = (float*)d_out;

  const int N = 480000;
  const int B = in_sizes[0] / N;   // 16
  const int TOT = out_size / B;    // 432000
  const int M = (TOT + 8) / 9;     // 48000 periods

  dim3 grid((M + RS_TPB - 1) / RS_TPB, B);
  resample_kernel<<<grid, RS_TPB, 0, stream>>>(wav, wgt, out, N, M, TOT);
}